// Round 15
// baseline (83.251 us; speedup 1.0000x reference)
//
#include <hip/hip_runtime.h>
#include <hip/hip_bf16.h>
#include <cstddef>
#include <cstdint>

#define N_ST 256
#define TWO_N 512
#define NU 128
#define BATCH 16
#define TSTEPS 2048
#define MTOT (BATCH * TSTEPS)   // 32768
#define H_STEP 0.01f
#define EPS_V 0.001f
#define NCHUNK 32
#define CHUNKL 64
#define NBLK (MTOT / CHUNKL)    // 512 chunk blocks

typedef __attribute__((ext_vector_type(4))) float f32x4;
typedef __attribute__((ext_vector_type(4))) short s16x4;
typedef __attribute__((ext_vector_type(8))) short s16x8;

#define AS1 __attribute__((address_space(1)))
#define AS3 __attribute__((address_space(3)))

// ---- workspace layout (float offsets) ----
#define OFF_UPK    0            // 4194304 shorts: packed bf16 u [(m>>4)][k=128][m&15]
#define OFF_WT     2097152      // 262144 shorts: packed Wt [(n>>4)][k=512][n&15]
#define OFF_WF     2228224      // 65536 shorts: packed Wf [(c>>4)][k=128][c&15]
#define OFF_D      2260992      // 1024 f32
#define OFF_XBAR0  2262016      // 8192 f32
#define OFF_E      2270208      // 512*512 f32
#define OFF_CINIT  2532352      // 512*512 f32

// ---- LDS byte map for chunk kernels (144 KB total) ----
#define F_B 0                   // 64 KB: F/Z natural [64 t][512 s] bf16, byte ^= (t&15)<<3
#define B_B 65536               // 64 KB: B stage double buffer (2 x 32 KB)
#define U_B 131072              // 16 KB: u-chunk packed [4 slabs][128 k][16]

static __device__ __forceinline__ float bf2f(short s) {
    return __uint_as_float(((unsigned)(unsigned short)s) << 16);
}
static __device__ __forceinline__ short f2bf(float f) {
    __hip_bfloat16 b = __float2bfloat16(f);
    return *reinterpret_cast<short*>(&b);
}

// ---- merged precompute: 0..1023 prep_W, 1024..1279 prep_Wf, 1280 prep_d,
// 1281..1344 xbar0, 1345..1856 upack ----
__global__ __launch_bounds__(256) void prep_mega(
    const float* __restrict__ P_re, const float* __restrict__ P_im,
    const float* __restrict__ B_re, const float* __restrict__ B_im,
    const float* __restrict__ alpha, const float* __restrict__ theta,
    const float* __restrict__ Pinv_re, const float* __restrict__ Pinv_im,
    const float* __restrict__ xi0, const float* __restrict__ u,
    short* __restrict__ Wtpk, short* __restrict__ Wfpk,
    float* __restrict__ dbuf, float* __restrict__ xbar0,
    short* __restrict__ upk)
{
    __shared__ float xs[BATCH * TWO_N];   // 32 KB
    int blk = blockIdx.x, tid = threadIdx.x;
    if (blk < 1024) {
        int idx = blk * 256 + tid;
        int j = idx >> 9, c = idx & 511;
        float v;
        if (c < N_ST) v = P_re[j * TWO_N + c] + P_re[j * TWO_N + c + N_ST];
        else          v = P_im[j * TWO_N + c] - P_im[j * TWO_N + c - N_ST];
        Wtpk[((size_t)(j >> 4) * TWO_N + c) * 16 + (j & 15)] = f2bf(v);
    } else if (blk < 1280) {
        int idx = (blk - 1024) * 256 + tid;
        int k = idx >> 9, c = idx & 511;
        float v = (c < N_ST) ? B_re[c * NU + k] : B_im[(c - N_ST) * NU + k];
        Wfpk[((size_t)(c >> 4) * NU + k) * 16 + (c & 15)] = f2bf(H_STEP * v);
    } else if (blk == 1280) {
        int i = tid;
        float dr = 1.0f + H_STEP * (-expf(alpha[i]) - EPS_V);
        float di = H_STEP * theta[i];
        float pr = 1.0f, pi = 0.0f;
        for (int k = 0; k < CHUNKL; ++k) { float nr = pr * dr - pi * di; pi = pr * di + pi * dr; pr = nr; }
        dbuf[i] = dr; dbuf[N_ST + i] = di; dbuf[2 * N_ST + i] = pr; dbuf[3 * N_ST + i] = pi;
    } else if (blk < 1345) {
#pragma unroll
        for (int q = 0; q < 8; ++q)
            *reinterpret_cast<float4*>(&xs[(q * 256 + tid) * 4]) =
                *reinterpret_cast<const float4*>(&xi0[(q * 256 + tid) * 4]);
        __syncthreads();
        int wv = tid >> 6, l = tid & 63;
        int i = (blk - 1281) * 4 + wv;
        float rp[BATCH] = {}, ip[BATCH] = {};
#pragma unroll
        for (int q = 0; q < 8; ++q) {
            int j = q * 64 + l;
            float pr = Pinv_re[(size_t)i * TWO_N + j];
            float pi = Pinv_im[(size_t)i * TWO_N + j];
#pragma unroll
            for (int b = 0; b < BATCH; ++b) {
                float x = xs[b * TWO_N + j];
                rp[b] = fmaf(pr, x, rp[b]);
                ip[b] = fmaf(pi, x, ip[b]);
            }
        }
#pragma unroll
        for (int m = 1; m < 64; m <<= 1) {
#pragma unroll
            for (int b = 0; b < BATCH; ++b) {
                rp[b] += __shfl_xor(rp[b], m, 64);
                ip[b] += __shfl_xor(ip[b], m, 64);
            }
        }
        if (l == 0) {
#pragma unroll
            for (int b = 0; b < BATCH; ++b) {
                xbar0[b * TWO_N + i] = rp[b];
                xbar0[b * TWO_N + N_ST + i] = ip[b];
            }
        }
    } else {
        short* st = (short*)xs;
        int bid = blk - 1345;             // 0..511
        const float* up = u + (size_t)bid * 8192;
#pragma unroll
        for (int q = 0; q < 8; ++q) {
            int idx = q * 1024 + tid * 4;
            float4 v = *reinterpret_cast<const float4*>(up + idx);
            int m = idx >> 7, k = idx & 127;
            s16x4 pv;
            pv[0] = f2bf(v.x); pv[1] = f2bf(v.y); pv[2] = f2bf(v.z); pv[3] = f2bf(v.w);
            *reinterpret_cast<__shared__ s16x4*>(&st[m * 132 + k]) = pv;
        }
        __syncthreads();
        short* op = upk + (size_t)bid * 8192;
#pragma unroll
        for (int q2 = 0; q2 < 4; ++q2) {
            int o = q2 * 2048 + tid * 8;
            int ml = o & 15, k = (o >> 4) & 127, sl = o >> 11;
            s16x8 w;
#pragma unroll
            for (int r = 0; r < 8; ++r) w[r] = st[(sl * 16 + ml + r) * 132 + k];
            *reinterpret_cast<s16x8*>(op + o) = w;
        }
    }
}

// ---- fused chunk kernel: 512 thr (8 waves), 144 KB LDS, 1 block/CU.
// Phase 1: F(64x512) = u_chunk @ Wf^T (K=128, MFMA, 2-buf counted-vmcnt).
// Phase 2: 64-step diagonal scan in LDS. FULL=false: write e, exit.
// Phase 3 (FULL): out(64x512) = Z @ Wt^T (K=512), Z read from LDS, Wt streamed.
template <bool FULL>
__global__ __launch_bounds__(512, 2) void chunk_kernel(
    const short* __restrict__ upk, const short* __restrict__ Wfpk,
    const short* __restrict__ Wtpk, const float* __restrict__ dbuf,
    const float* __restrict__ cinit, float* __restrict__ e,
    const float* __restrict__ xi0, float* __restrict__ out)
{
    __shared__ __align__(1024) short lds[73728];   // 144 KB
    char* smem = (char*)lds;
    const int tid = threadIdx.x;
    const int w = tid >> 6, lane = tid & 63;
    const int laneL = lane & 15, laneH = lane >> 4;
    const int cid = blockIdx.x;                    // chunk 0..511
    const unsigned ldsA = (unsigned)(uintptr_t)(AS3 short*)&lds[0];

    // ---------------- Phase 1: forcing GEMM ----------------
    {   // stage u-chunk (16 KB, once): wave w loads 2 x 1KB
        const short* usrc = upk + (size_t)(cid * 4) * 2048;
#pragma unroll
        for (int q = 0; q < 2; ++q) {
            int c_ = w * 2 + q;
            __builtin_amdgcn_global_load_lds((const AS1 void*)(usrc + c_ * 512 + lane * 8),
                (AS3 void*)(smem + U_B + c_ * 1024), 16, 0, 0);
        }
    }
#define STAGE_B(Wsrc, slabStrideShorts, buf, kk)                                                    \
    do {                                                                                            \
        _Pragma("unroll")                                                                           \
        for (int q_ = 0; q_ < 4; ++q_) {                                                            \
            int s_ = w + q_ * 8;                                                                    \
            __builtin_amdgcn_global_load_lds(                                                       \
                (const AS1 void*)((Wsrc) + (size_t)s_ * (slabStrideShorts) + (size_t)(kk) * 16 + lane * 8), \
                (AS3 void*)(smem + B_B + (buf) * 32768 + s_ * 1024), 16, 0, 0);                     \
        }                                                                                           \
    } while (0)

    f32x4 acc[4][4] = {};
    STAGE_B(Wfpk, 2048, 0, 0);
#pragma unroll
    for (int t = 0; t < 4; ++t) {
        const int buf = t & 1;
        if (t + 1 < 4) STAGE_B(Wfpk, 2048, buf ^ 1, (t + 1) * 32);
        if (t + 1 < 4) asm volatile("s_waitcnt vmcnt(4)" ::: "memory");
        else           asm volatile("s_waitcnt vmcnt(0)" ::: "memory");
        __builtin_amdgcn_sched_barrier(0);
        __builtin_amdgcn_s_barrier();        // barrier 1: stage t landed
        __builtin_amdgcn_sched_barrier(0);

        s16x4 al[4], ah[4], bl[4], bh[4];
#pragma unroll
        for (int i = 0; i < 4; ++i) {
            unsigned ad = ldsA + U_B + (unsigned)i * 4096u + (unsigned)t * 1024u + ((unsigned)lane << 3);
            asm volatile("ds_read_b64_tr_b16 %0, %1 offset:0"   : "=v"(al[i]) : "v"(ad));
            asm volatile("ds_read_b64_tr_b16 %0, %1 offset:512" : "=v"(ah[i]) : "v"(ad));
        }
#pragma unroll
        for (int j = 0; j < 4; ++j) {
            unsigned bd = ldsA + B_B + (unsigned)buf * 32768u + ((unsigned)(w * 4 + j) << 10) + ((unsigned)lane << 3);
            asm volatile("ds_read_b64_tr_b16 %0, %1 offset:0"   : "=v"(bl[j]) : "v"(bd));
            asm volatile("ds_read_b64_tr_b16 %0, %1 offset:512" : "=v"(bh[j]) : "v"(bd));
        }
        asm volatile("s_waitcnt lgkmcnt(0)" ::: "memory");
        __builtin_amdgcn_sched_barrier(0);   // rule 18
        __builtin_amdgcn_s_barrier();        // barrier 2: all reads of buf done
        __builtin_amdgcn_sched_barrier(0);

        __builtin_amdgcn_s_setprio(1);
#pragma unroll
        for (int i = 0; i < 4; ++i) {
            s16x8 av = __builtin_shufflevector(al[i], ah[i], 0, 1, 2, 3, 4, 5, 6, 7);
#pragma unroll
            for (int j = 0; j < 4; ++j) {
                s16x8 bv = __builtin_shufflevector(bl[j], bh[j], 0, 1, 2, 3, 4, 5, 6, 7);
                acc[i][j] = __builtin_amdgcn_mfma_f32_16x16x32_bf16(av, bv, acc[i][j], 0, 0, 0);
            }
        }
        __builtin_amdgcn_s_setprio(0);
    }
    // epilogue: F(t, s) -> LDS natural, byte = t*1024 + ((2s) ^ ((t&15)<<3))
#pragma unroll
    for (int i = 0; i < 4; ++i) {
#pragma unroll
        for (int j = 0; j < 4; ++j) {
            int s = w * 64 + j * 16 + laneL;
#pragma unroll
            for (int r = 0; r < 4; ++r) {
                int t = i * 16 + laneH * 4 + r;
                *(short*)(smem + F_B + t * 1024 + (((unsigned)(2 * s)) ^ (unsigned)((t & 15) << 3))) =
                    f2bf(acc[i][j][r]);
            }
        }
    }
    __syncthreads();   // F published (full drain OK here, once)

    // pre-issue Wt K-step 0 during the scan (hides L2 latency)
    if (FULL) STAGE_B(Wtpk, 8192, 0, 0);

    // ---------------- Phase 2: diagonal scan ----------------
    if (tid < 256) {
        const int i2 = tid;
        float dr = dbuf[i2], di = dbuf[N_ST + i2];
        float re, im;
        if (FULL) { re = cinit[(size_t)cid * TWO_N + i2]; im = cinit[(size_t)cid * TWO_N + N_ST + i2]; }
        else      { re = 0.f; im = 0.f; }
        const unsigned colr = (unsigned)(2 * i2);
#pragma unroll 8
        for (int t = 0; t < CHUNKL; ++t) {
            char* p = smem + F_B + t * 1024 + (colr ^ (unsigned)((t & 15) << 3));
            float fr = bf2f(*(short*)p);
            float fi = bf2f(*(short*)(p + 512));
            float nre = fmaf(dr, re, fmaf(-di, im, fr));
            float nim = fmaf(dr, im, fmaf(di, re, fi));
            re = nre; im = nim;
            if (FULL) { *(short*)p = f2bf(re); *(short*)(p + 512) = f2bf(im); }
        }
        if (!FULL) {
            e[(size_t)cid * TWO_N + i2] = re;
            e[(size_t)cid * TWO_N + N_ST + i2] = im;
        }
    }
    if (!FULL) return;
    __syncthreads();   // Z published

    // ---------------- Phase 3: out = Z @ Wt^T (K=512) ----------------
    f32x4 acc2[4][4] = {};
#pragma unroll
    for (int t = 0; t < 16; ++t) {
        const int buf = t & 1;
        if (t + 1 < 16) STAGE_B(Wtpk, 8192, buf ^ 1, (t + 1) * 32);
        if (t + 1 < 16) asm volatile("s_waitcnt vmcnt(4)" ::: "memory");
        else            asm volatile("s_waitcnt vmcnt(0)" ::: "memory");
        __builtin_amdgcn_sched_barrier(0);
        __builtin_amdgcn_s_barrier();        // barrier 1
        __builtin_amdgcn_sched_barrier(0);

        // A-frags straight from Z in LDS (plain b64 pairs; Z is read-only now)
        s16x8 av[4];
        {
            const unsigned klo = (unsigned)((t * 32 + laneH * 4) * 2);
            const unsigned swz = (unsigned)(laneL << 3);
#pragma unroll
            for (int i = 0; i < 4; ++i) {
                char* base = smem + F_B + (i * 16 + laneL) * 1024;
                s16x4 lo = *(const s16x4*)(base + (klo ^ swz));
                s16x4 hi = *(const s16x4*)(base + ((klo + 32) ^ swz));
                av[i] = __builtin_shufflevector(lo, hi, 0, 1, 2, 3, 4, 5, 6, 7);
            }
        }
        s16x4 bl[4], bh[4];
#pragma unroll
        for (int j = 0; j < 4; ++j) {
            unsigned bd = ldsA + B_B + (unsigned)buf * 32768u + ((unsigned)(w * 4 + j) << 10) + ((unsigned)lane << 3);
            asm volatile("ds_read_b64_tr_b16 %0, %1 offset:0"   : "=v"(bl[j]) : "v"(bd));
            asm volatile("ds_read_b64_tr_b16 %0, %1 offset:512" : "=v"(bh[j]) : "v"(bd));
        }
        asm volatile("s_waitcnt lgkmcnt(0)" ::: "memory");
        __builtin_amdgcn_sched_barrier(0);   // rule 18
        __builtin_amdgcn_s_barrier();        // barrier 2
        __builtin_amdgcn_sched_barrier(0);

        __builtin_amdgcn_s_setprio(1);
#pragma unroll
        for (int j = 0; j < 4; ++j) {
            s16x8 bv = __builtin_shufflevector(bl[j], bh[j], 0, 1, 2, 3, 4, 5, 6, 7);
#pragma unroll
            for (int i = 0; i < 4; ++i)
                acc2[i][j] = __builtin_amdgcn_mfma_f32_16x16x32_bf16(av[i], bv, acc2[i][j], 0, 0, 0);
        }
        __builtin_amdgcn_s_setprio(0);
    }
#undef STAGE_B

    // epilogue: out rows cid*64 + i*16 + laneH*4 + r, cols w*64 + j*16 + laneL
#pragma unroll
    for (int i = 0; i < 4; ++i) {
        int mrow = cid * 64 + i * 16 + laneH * 4;
#pragma unroll
        for (int j = 0; j < 4; ++j) {
            int ncol = w * 64 + j * 16 + laneL;
            float* cp = out + (size_t)mrow * TWO_N + ncol;
#pragma unroll
            for (int r = 0; r < 4; ++r) {
                float v = acc2[i][j][r];
                if (((mrow + r) & (TSTEPS - 1)) == 0)   // t==0 row: out = xi_init
                    v = xi0[((mrow + r) >> 11) * TWO_N + ncol];
                cp[(size_t)r * TWO_N] = v;
            }
        }
    }
}

// ---- sequential cross-chunk combine ----
__global__ void scan_passB(const float* __restrict__ e, const float* __restrict__ dbuf,
                           const float* __restrict__ xbar0, float* __restrict__ cinit) {
    int b = blockIdx.x, i = threadIdx.x;
    float dLr = dbuf[2 * N_ST + i], dLi = dbuf[3 * N_ST + i];
    float re = xbar0[b * TWO_N + i], im = xbar0[b * TWO_N + N_ST + i];
    for (int c = 0; c < NCHUNK; ++c) {
        size_t o = ((size_t)(b * NCHUNK + c)) * TWO_N;
        cinit[o + i] = re;
        cinit[o + N_ST + i] = im;
        float er = e[o + i], ei = e[o + N_ST + i];
        float nre = fmaf(dLr, re, fmaf(-dLi, im, er));
        float nim = fmaf(dLr, im, fmaf(dLi, re, ei));
        re = nre; im = nim;
    }
}

extern "C" void kernel_launch(void* const* d_in, const int* in_sizes, int n_in,
                              void* d_out, int out_size, void* d_ws, size_t ws_size,
                              hipStream_t stream) {
    const float* xi_init = (const float*)d_in[0];
    const float* u_log   = (const float*)d_in[1];
    const float* alpha   = (const float*)d_in[2];
    const float* theta   = (const float*)d_in[3];
    const float* B_re    = (const float*)d_in[4];
    const float* B_im    = (const float*)d_in[5];
    const float* P_re    = (const float*)d_in[6];
    const float* P_im    = (const float*)d_in[7];
    const float* Pinv_re = (const float*)d_in[8];
    const float* Pinv_im = (const float*)d_in[9];
    float* out = (float*)d_out;
    float* ws  = (float*)d_ws;

    short* upk  = (short*)(ws + OFF_UPK);
    short* Wtpk = (short*)(ws + OFF_WT);
    short* Wfpk = (short*)(ws + OFF_WF);
    float* dbuf  = ws + OFF_D;
    float* xbar0 = ws + OFF_XBAR0;
    float* e     = ws + OFF_E;
    float* cinit = ws + OFF_CINIT;

    prep_mega<<<1857, 256, 0, stream>>>(P_re, P_im, B_re, B_im, alpha, theta,
                                        Pinv_re, Pinv_im, xi_init, u_log,
                                        Wtpk, Wfpk, dbuf, xbar0, upk);

    // K1: forcing + chunk-local scan -> e  (F stays in LDS)
    chunk_kernel<false><<<NBLK, 512, 0, stream>>>(
        upk, Wfpk, Wtpk, dbuf, nullptr, e, nullptr, nullptr);

    // cross-chunk combine
    scan_passB<<<BATCH, 256, 0, stream>>>(e, dbuf, xbar0, cinit);

    // K3: forcing + scan from cinit + output projection (Z stays in LDS)
    chunk_kernel<true><<<NBLK, 512, 0, stream>>>(
        upk, Wfpk, Wtpk, dbuf, cinit, nullptr, xi_init, out);
}

// Round 16
// 71.628 us; speedup vs baseline: 1.1623x; 1.1623x over previous
//
#include <hip/hip_runtime.h>
#include <hip/hip_bf16.h>
#include <cstddef>
#include <cstdint>

#define N_ST 256
#define TWO_N 512
#define NU 128
#define BATCH 16
#define TSTEPS 2048
#define MTOT (BATCH * TSTEPS)   // 32768
#define H_STEP 0.01f
#define EPS_V 0.001f
#define NCHUNK 32
#define CHUNKL 64

typedef __attribute__((ext_vector_type(4))) float f32x4;
typedef __attribute__((ext_vector_type(4))) short s16x4;
typedef __attribute__((ext_vector_type(8))) short s16x8;

#define AS1 __attribute__((address_space(1)))
#define AS3 __attribute__((address_space(3)))

// ---- workspace layout (float offsets) ----
#define OFF_FPK    0            // 16777216 shorts: packed bf16 F [(m>>4)][k=512][m&15]
#define OFF_ZPK    8388608      // 16777216 shorts: packed bf16 Z, same layout
#define OFF_UPK    16777216     // 4194304 shorts: packed bf16 u [(m>>4)][k=128][m&15]
#define OFF_WT     18874368     // 262144 shorts
#define OFF_WF     19005440     // 65536 shorts
#define OFF_D      19038208     // 1024 f32
#define OFF_XBAR0  19039232     // 8192 f32
#define OFF_E      19047424     // 512*512 f32

static __device__ __forceinline__ float bf2f(short s) {
    return __uint_as_float(((unsigned)(unsigned short)s) << 16);
}
static __device__ __forceinline__ short f2bf(float f) {
    __hip_bfloat16 b = __float2bfloat16(f);
    return *reinterpret_cast<short*>(&b);
}

// ---- merged precompute: blocks 0..1023 prep_W, 1024..1279 prep_Wf, 1280 prep_d,
// 1281..1344 xbar0 (64), 1345..1856 upack (512) ----
__global__ __launch_bounds__(256) void prep_mega(
    const float* __restrict__ P_re, const float* __restrict__ P_im,
    const float* __restrict__ B_re, const float* __restrict__ B_im,
    const float* __restrict__ alpha, const float* __restrict__ theta,
    const float* __restrict__ Pinv_re, const float* __restrict__ Pinv_im,
    const float* __restrict__ xi0, const float* __restrict__ u,
    short* __restrict__ Wtpk, short* __restrict__ Wfpk,
    float* __restrict__ dbuf, float* __restrict__ xbar0,
    short* __restrict__ upk)
{
    __shared__ float xs[BATCH * TWO_N];   // 32 KB
    int blk = blockIdx.x, tid = threadIdx.x;
    if (blk < 1024) {
        int idx = blk * 256 + tid;
        int j = idx >> 9, c = idx & 511;
        float v;
        if (c < N_ST) v = P_re[j * TWO_N + c] + P_re[j * TWO_N + c + N_ST];
        else          v = P_im[j * TWO_N + c] - P_im[j * TWO_N + c - N_ST];
        Wtpk[((size_t)(j >> 4) * TWO_N + c) * 16 + (j & 15)] = f2bf(v);
    } else if (blk < 1280) {
        int idx = (blk - 1024) * 256 + tid;
        int k = idx >> 9, c = idx & 511;
        float v = (c < N_ST) ? B_re[c * NU + k] : B_im[(c - N_ST) * NU + k];
        Wfpk[((size_t)(c >> 4) * NU + k) * 16 + (c & 15)] = f2bf(H_STEP * v);
    } else if (blk == 1280) {
        int i = tid;
        float dr = 1.0f + H_STEP * (-expf(alpha[i]) - EPS_V);
        float di = H_STEP * theta[i];
        float pr = 1.0f, pi = 0.0f;
        for (int k = 0; k < CHUNKL; ++k) { float nr = pr * dr - pi * di; pi = pr * di + pi * dr; pr = nr; }
        dbuf[i] = dr; dbuf[N_ST + i] = di; dbuf[2 * N_ST + i] = pr; dbuf[3 * N_ST + i] = pi;
    } else if (blk < 1345) {
#pragma unroll
        for (int q = 0; q < 8; ++q)
            *reinterpret_cast<float4*>(&xs[(q * 256 + tid) * 4]) =
                *reinterpret_cast<const float4*>(&xi0[(q * 256 + tid) * 4]);
        __syncthreads();
        int wv = tid >> 6, l = tid & 63;
        int i = (blk - 1281) * 4 + wv;
        float rp[BATCH] = {}, ip[BATCH] = {};
#pragma unroll
        for (int q = 0; q < 8; ++q) {
            int j = q * 64 + l;
            float pr = Pinv_re[(size_t)i * TWO_N + j];
            float pi = Pinv_im[(size_t)i * TWO_N + j];
#pragma unroll
            for (int b = 0; b < BATCH; ++b) {
                float x = xs[b * TWO_N + j];
                rp[b] = fmaf(pr, x, rp[b]);
                ip[b] = fmaf(pi, x, ip[b]);
            }
        }
#pragma unroll
        for (int m = 1; m < 64; m <<= 1) {
#pragma unroll
            for (int b = 0; b < BATCH; ++b) {
                rp[b] += __shfl_xor(rp[b], m, 64);
                ip[b] += __shfl_xor(ip[b], m, 64);
            }
        }
        if (l == 0) {
#pragma unroll
            for (int b = 0; b < BATCH; ++b) {
                xbar0[b * TWO_N + i] = rp[b];
                xbar0[b * TWO_N + N_ST + i] = ip[b];
            }
        }
    } else {
        short* st = (short*)xs;
        int bid = blk - 1345;             // 0..511
        const float* up = u + (size_t)bid * 8192;
#pragma unroll
        for (int q = 0; q < 8; ++q) {
            int idx = q * 1024 + tid * 4;
            float4 v = *reinterpret_cast<const float4*>(up + idx);
            int m = idx >> 7, k = idx & 127;
            s16x4 pv;
            pv[0] = f2bf(v.x); pv[1] = f2bf(v.y); pv[2] = f2bf(v.z); pv[3] = f2bf(v.w);
            *reinterpret_cast<__shared__ s16x4*>(&st[m * 132 + k]) = pv;
        }
        __syncthreads();
        short* op = upk + (size_t)bid * 8192;
#pragma unroll
        for (int q2 = 0; q2 < 4; ++q2) {
            int o = q2 * 2048 + tid * 8;
            int ml = o & 15, k = (o >> 4) & 127, sl = o >> 11;
            s16x8 w;
#pragma unroll
            for (int r = 0; r < 8; ++r) w[r] = st[(sl * 16 + ml + r) * 132 + k];
            *reinterpret_cast<s16x8*>(op + o) = w;
        }
    }
}

// ---- gemm1 + chunk-local scan fused: BM=64 (1 chunk), BN=512, 8 waves.
// K-loop: 2-buf counted vmcnt + two raw barriers (round-15-verified skeleton).
// Epilogue: write Fpk (packed global) + F -> LDS (swizzled) -> in-block scan -> e.
__global__ __launch_bounds__(512, 2) void chunk_fgemm(
    const short* __restrict__ upk, const short* __restrict__ Wfpk,
    const float* __restrict__ dbuf, short* __restrict__ Fpk,
    float* __restrict__ e)
{
    __shared__ __align__(1024) short lds[36864];   // 72 KB: A 2x4KB, B 2x32KB; reused for F 64KB
    char* smem = (char*)lds;
    const int tid = threadIdx.x;
    const int w = tid >> 6, lane = tid & 63;
    const int laneL = lane & 15, laneH = lane >> 4;
    const int cid = blockIdx.x;                    // chunk 0..511, rows cid*64..cid*64+63
    const unsigned ldsA = (unsigned)(uintptr_t)(AS3 short*)&lds[0];
    f32x4 acc[4][4] = {};

    // stage: 4 B-slabs per wave + (waves 0-3) 1 A-slab. 36 loads total.
#define STG(buf, kk)                                                                                \
    do {                                                                                            \
        _Pragma("unroll")                                                                           \
        for (int q_ = 0; q_ < 4; ++q_) {                                                            \
            int sb_ = w + q_ * 8;                                                                   \
            __builtin_amdgcn_global_load_lds(                                                       \
                (const AS1 void*)(Wfpk + (size_t)sb_ * 2048 + (size_t)(kk) * 16 + lane * 8),        \
                (AS3 void*)(smem + 8192 + (buf) * 32768 + sb_ * 1024), 16, 0, 0);                   \
        }                                                                                           \
        if (w < 4) {                                                                                \
            __builtin_amdgcn_global_load_lds(                                                       \
                (const AS1 void*)(upk + (size_t)(cid * 4 + w) * 2048 + (size_t)(kk) * 16 + lane * 8), \
                (AS3 void*)(smem + (buf) * 4096 + w * 1024), 16, 0, 0);                             \
        }                                                                                           \
    } while (0)

    STG(0, 0);
#pragma unroll
    for (int t = 0; t < 4; ++t) {
        const int buf = t & 1;
        if (t < 3) STG(buf ^ 1, (t + 1) * 32);
        // counted wait: stage t landed; stage t+1 stays in flight (per-wave own count)
        if (t < 3) {
            if (w < 4) asm volatile("s_waitcnt vmcnt(5)" ::: "memory");
            else       asm volatile("s_waitcnt vmcnt(4)" ::: "memory");
        } else {
            asm volatile("s_waitcnt vmcnt(0)" ::: "memory");
        }
        __builtin_amdgcn_sched_barrier(0);
        __builtin_amdgcn_s_barrier();        // barrier 1: all waves' buf[cur] loads complete
        __builtin_amdgcn_sched_barrier(0);

        s16x4 al[4], ah[4], bl[4], bh[4];
#pragma unroll
        for (int i = 0; i < 4; ++i) {
            unsigned ad = ldsA + (unsigned)buf * 4096u + (unsigned)i * 1024u + ((unsigned)lane << 3);
            asm volatile("ds_read_b64_tr_b16 %0, %1 offset:0"   : "=v"(al[i]) : "v"(ad));
            asm volatile("ds_read_b64_tr_b16 %0, %1 offset:512" : "=v"(ah[i]) : "v"(ad));
        }
#pragma unroll
        for (int j = 0; j < 4; ++j) {
            unsigned bd = ldsA + 8192u + (unsigned)buf * 32768u + ((unsigned)(w * 4 + j) << 10) + ((unsigned)lane << 3);
            asm volatile("ds_read_b64_tr_b16 %0, %1 offset:0"   : "=v"(bl[j]) : "v"(bd));
            asm volatile("ds_read_b64_tr_b16 %0, %1 offset:512" : "=v"(bh[j]) : "v"(bd));
        }
        asm volatile("s_waitcnt lgkmcnt(0)" ::: "memory");
        __builtin_amdgcn_sched_barrier(0);   // rule 18
        __builtin_amdgcn_s_barrier();        // barrier 2: all waves done reading buf[cur]
        __builtin_amdgcn_sched_barrier(0);

        __builtin_amdgcn_s_setprio(1);
#pragma unroll
        for (int i = 0; i < 4; ++i) {
            s16x8 av = __builtin_shufflevector(al[i], ah[i], 0, 1, 2, 3, 4, 5, 6, 7);
#pragma unroll
            for (int j = 0; j < 4; ++j) {
                s16x8 bv = __builtin_shufflevector(bl[j], bh[j], 0, 1, 2, 3, 4, 5, 6, 7);
                acc[i][j] = __builtin_amdgcn_mfma_f32_16x16x32_bf16(av, bv, acc[i][j], 0, 0, 0);
            }
        }
        __builtin_amdgcn_s_setprio(0);
    }
#undef STG

    // ---- epilogue A: Fpk packed global (row = i*16+laneH*4+r, col = w*64+j*16+laneL)
    const int g4 = laneH * 4;
#pragma unroll
    for (int i = 0; i < 4; ++i) {
        size_t slab = (size_t)(cid * 4 + i);
#pragma unroll
        for (int j = 0; j < 4; ++j) {
            int n = w * 64 + j * 16 + laneL;
            s16x4 pv;
#pragma unroll
            for (int r = 0; r < 4; ++r) pv[r] = f2bf(acc[i][j][r]);
            *reinterpret_cast<s16x4*>(Fpk + slab * 8192 + (size_t)n * 16 + g4) = pv;
        }
    }
    // ---- epilogue B: F -> LDS natural [64t][512s], byte = t*1024 + ((2s)^((t&15)<<3))
    // (safe: all waves past barrier 2 of last K-step; LDS is dead)
#pragma unroll
    for (int i = 0; i < 4; ++i) {
#pragma unroll
        for (int j = 0; j < 4; ++j) {
            int s = w * 64 + j * 16 + laneL;
#pragma unroll
            for (int r = 0; r < 4; ++r) {
                int t = i * 16 + laneH * 4 + r;
                *(short*)(smem + t * 1024 + (((unsigned)(2 * s)) ^ (unsigned)((t & 15) << 3))) =
                    f2bf(acc[i][j][r]);
            }
        }
    }
    __syncthreads();
    // ---- epilogue C: chunk-local scan (bit-identical to old scan_passA)
    if (tid < 256) {
        const int i2 = tid;
        float dr = dbuf[i2], di = dbuf[N_ST + i2];
        float re = 0.f, im = 0.f;
        const unsigned colr = (unsigned)(2 * i2);
#pragma unroll 8
        for (int t = 0; t < CHUNKL; ++t) {
            char* p = smem + t * 1024 + (colr ^ (unsigned)((t & 15) << 3));
            float fr = bf2f(*(short*)p);
            float fi = bf2f(*(short*)(p + 512));
            float nre = fmaf(dr, re, fmaf(-di, im, fr));
            float nim = fmaf(dr, im, fmaf(di, re, fi));
            re = nre; im = nim;
        }
        e[(size_t)cid * TWO_N + i2] = re;
        e[(size_t)cid * TWO_N + N_ST + i2] = im;
    }
}

// ---- scanC with integrated cross-chunk prefix (round-13 verbatim) ----
__global__ __launch_bounds__(256) void scan_passC(const short* __restrict__ Fpk,
                                                  const float* __restrict__ dbuf,
                                                  const float* __restrict__ e,
                                                  const float* __restrict__ xbar0,
                                                  short* __restrict__ Zpk) {
    int b = blockIdx.x, c = blockIdx.y, i = threadIdx.x;
    float dr = dbuf[i], di = dbuf[N_ST + i];
    float dLr = dbuf[2 * N_ST + i], dLi = dbuf[3 * N_ST + i];
    float re = xbar0[b * TWO_N + i], im = xbar0[b * TWO_N + N_ST + i];
    for (int cc = 0; cc < c; ++cc) {
        size_t o = ((size_t)(b * NCHUNK + cc)) * TWO_N;
        float er = e[o + i], ei = e[o + N_ST + i];
        float nre = fmaf(dLr, re, fmaf(-dLi, im, er));
        float nim = fmaf(dLr, im, fmaf(dLi, re, ei));
        re = nre; im = nim;
    }
    int slab0 = (b * TSTEPS + c * CHUNKL) >> 4;
#pragma unroll
    for (int g = 0; g < 4; ++g) {
        const short* base = Fpk + (size_t)(slab0 + g) * 8192 + i * 16;
        s16x8 r0 = *reinterpret_cast<const s16x8*>(base);
        s16x8 r1 = *reinterpret_cast<const s16x8*>(base + 8);
        s16x8 i0 = *reinterpret_cast<const s16x8*>(base + 4096);
        s16x8 i1 = *reinterpret_cast<const s16x8*>(base + 4096 + 8);
        s16x8 zr0, zr1, zi0, zi1;
#pragma unroll
        for (int j = 0; j < 16; ++j) {
            float fr = bf2f(j < 8 ? r0[j & 7] : r1[j & 7]);
            float fi = bf2f(j < 8 ? i0[j & 7] : i1[j & 7]);
            float nre = fmaf(dr, re, fmaf(-di, im, fr));
            float nim = fmaf(dr, im, fmaf(di, re, fi));
            re = nre; im = nim;
            if (j < 8) { zr0[j & 7] = f2bf(re); zi0[j & 7] = f2bf(im); }
            else       { zr1[j & 7] = f2bf(re); zi1[j & 7] = f2bf(im); }
        }
        short* zb = Zpk + (size_t)(slab0 + g) * 8192 + i * 16;
        *reinterpret_cast<s16x8*>(zb)            = zr0;
        *reinterpret_cast<s16x8*>(zb + 8)        = zr1;
        *reinterpret_cast<s16x8*>(zb + 4096)     = zi0;
        *reinterpret_cast<s16x8*>(zb + 4096 + 8) = zi1;
    }
}

// ---- output GEMM: 256x256 tile, 8 waves, 3-deep ring (round-13 verbatim, de-templated)
__global__ __launch_bounds__(512, 2) void gemm_out(const short* __restrict__ Apk,
                                                   const short* __restrict__ Bpk,
                                                   float* __restrict__ Cf,
                                                   const float* __restrict__ xi0) {
    __shared__ __align__(1024) short lds[49152];   // A: buf*8192 (3 bufs), B: 24576 + buf*8192
    const int tid = threadIdx.x;
    const int wid = tid >> 6, lane = tid & 63;
    const int l = blockIdx.x;
    const int mb = ((l >> 4) << 3) | (l & 7);      // XCD-pairing swizzle
    const int nb = (l >> 3) & 1;
    const int m0 = mb * 256, n0 = nb * 256;
    const int wm = wid >> 2, wn = wid & 3;         // wave tile 128x64
    f32x4 acc[8][4] = {};
    const size_t slabStride = (size_t)TWO_N * 16;
    const unsigned ldsBase = (unsigned)(uintptr_t)(AS3 short*)&lds[0];
    constexpr int NT = TWO_N / 32;                 // 16

#define STAGE(buf, kk)                                                                              \
    do {                                                                                            \
        const short* gA0 = Apk + ((size_t)(m0 >> 4) + wid)     * slabStride + (size_t)(kk) * 16 + lane * 8; \
        const short* gA1 = Apk + ((size_t)(m0 >> 4) + wid + 8) * slabStride + (size_t)(kk) * 16 + lane * 8; \
        const short* gB0 = Bpk + ((size_t)(n0 >> 4) + wid)     * slabStride + (size_t)(kk) * 16 + lane * 8; \
        const short* gB1 = Bpk + ((size_t)(n0 >> 4) + wid + 8) * slabStride + (size_t)(kk) * 16 + lane * 8; \
        __builtin_amdgcn_global_load_lds((const AS1 void*)gA0,                                      \
            (AS3 void*)&lds[(buf) * 8192 + wid * 512], 16, 0, 0);                                   \
        __builtin_amdgcn_global_load_lds((const AS1 void*)gA1,                                      \
            (AS3 void*)&lds[(buf) * 8192 + (wid + 8) * 512], 16, 0, 0);                             \
        __builtin_amdgcn_global_load_lds((const AS1 void*)gB0,                                      \
            (AS3 void*)&lds[24576 + (buf) * 8192 + wid * 512], 16, 0, 0);                           \
        __builtin_amdgcn_global_load_lds((const AS1 void*)gB1,                                      \
            (AS3 void*)&lds[24576 + (buf) * 8192 + (wid + 8) * 512], 16, 0, 0);                     \
    } while (0)

    STAGE(0, 0);
    STAGE(1, 32);

#pragma unroll
    for (int t = 0; t < NT; ++t) {
        const int cur = t % 3;
        if (t + 2 < NT) STAGE((t + 2) % 3, (t + 2) * 32);

        if (t + 2 < NT)      asm volatile("s_waitcnt vmcnt(8)" ::: "memory");
        else if (t + 1 < NT) asm volatile("s_waitcnt vmcnt(4)" ::: "memory");
        else                 asm volatile("s_waitcnt vmcnt(0)" ::: "memory");
        __builtin_amdgcn_sched_barrier(0);
        __builtin_amdgcn_s_barrier();        // barrier 1
        __builtin_amdgcn_sched_barrier(0);

        s16x4 al[8], ah[8], bl[4], bh[4];
        const unsigned aB = ldsBase + (unsigned)cur * 16384u;
        const unsigned bB = ldsBase + 49152u + (unsigned)cur * 16384u;
#pragma unroll
        for (int i = 0; i < 8; ++i) {
            unsigned ad = aB + ((unsigned)(wm * 8 + i) << 10) + ((unsigned)lane << 3);
            asm volatile("ds_read_b64_tr_b16 %0, %1 offset:0"   : "=v"(al[i]) : "v"(ad));
            asm volatile("ds_read_b64_tr_b16 %0, %1 offset:512" : "=v"(ah[i]) : "v"(ad));
        }
#pragma unroll
        for (int j = 0; j < 4; ++j) {
            unsigned bd = bB + ((unsigned)(wn * 4 + j) << 10) + ((unsigned)lane << 3);
            asm volatile("ds_read_b64_tr_b16 %0, %1 offset:0"   : "=v"(bl[j]) : "v"(bd));
            asm volatile("ds_read_b64_tr_b16 %0, %1 offset:512" : "=v"(bh[j]) : "v"(bd));
        }
        asm volatile("s_waitcnt lgkmcnt(0)" ::: "memory");
        __builtin_amdgcn_sched_barrier(0);   // rule 18
        __builtin_amdgcn_s_barrier();        // barrier 2
        __builtin_amdgcn_sched_barrier(0);

        __builtin_amdgcn_s_setprio(1);
#pragma unroll
        for (int i = 0; i < 8; ++i) {
            s16x8 av = __builtin_shufflevector(al[i], ah[i], 0, 1, 2, 3, 4, 5, 6, 7);
#pragma unroll
            for (int j = 0; j < 4; ++j) {
                s16x8 bv = __builtin_shufflevector(bl[j], bh[j], 0, 1, 2, 3, 4, 5, 6, 7);
                acc[i][j] = __builtin_amdgcn_mfma_f32_16x16x32_bf16(av, bv, acc[i][j], 0, 0, 0);
            }
        }
        __builtin_amdgcn_s_setprio(0);
    }
#undef STAGE

    const int cn = lane & 15;
    const int g4 = (lane >> 4) * 4;
#pragma unroll
    for (int i = 0; i < 8; ++i) {
        int mrow = m0 + wm * 128 + i * 16 + g4;
#pragma unroll
        for (int j = 0; j < 4; ++j) {
            int ncol = n0 + wn * 64 + j * 16 + cn;
            float* cp = Cf + (size_t)mrow * TWO_N + ncol;
#pragma unroll
            for (int r = 0; r < 4; ++r) {
                float v = acc[i][j][r];
                if (((mrow + r) & (TSTEPS - 1)) == 0)   // t==0 row: out = xi_init
                    v = xi0[((mrow + r) >> 11) * TWO_N + ncol];
                cp[(size_t)r * TWO_N] = v;
            }
        }
    }
}

extern "C" void kernel_launch(void* const* d_in, const int* in_sizes, int n_in,
                              void* d_out, int out_size, void* d_ws, size_t ws_size,
                              hipStream_t stream) {
    const float* xi_init = (const float*)d_in[0];
    const float* u_log   = (const float*)d_in[1];
    const float* alpha   = (const float*)d_in[2];
    const float* theta   = (const float*)d_in[3];
    const float* B_re    = (const float*)d_in[4];
    const float* B_im    = (const float*)d_in[5];
    const float* P_re    = (const float*)d_in[6];
    const float* P_im    = (const float*)d_in[7];
    const float* Pinv_re = (const float*)d_in[8];
    const float* Pinv_im = (const float*)d_in[9];
    float* out = (float*)d_out;
    float* ws  = (float*)d_ws;

    short* Fpk  = (short*)(ws + OFF_FPK);
    short* Zpk  = (short*)(ws + OFF_ZPK);
    short* upk  = (short*)(ws + OFF_UPK);
    short* Wtpk = (short*)(ws + OFF_WT);
    short* Wfpk = (short*)(ws + OFF_WF);
    float* dbuf  = ws + OFF_D;
    float* xbar0 = ws + OFF_XBAR0;
    float* e     = ws + OFF_E;

    prep_mega<<<1857, 256, 0, stream>>>(P_re, P_im, B_re, B_im, alpha, theta,
                                        Pinv_re, Pinv_im, xi_init, u_log,
                                        Wtpk, Wfpk, dbuf, xbar0, upk);

    // gemm1 + chunk-local scan fused (scanA deleted)
    chunk_fgemm<<<MTOT / CHUNKL, 512, 0, stream>>>(upk, Wfpk, dbuf, Fpk, e);

    // cross-chunk prefix + Z emit
    scan_passC<<<dim3(BATCH, NCHUNK), 256, 0, stream>>>(Fpk, dbuf, e, xbar0, Zpk);

    // output projection
    gemm_out<<<256, 512, 0, stream>>>(Zpk, Wtpk, out, xi_init);
}